// Round 9
// baseline (130.778 us; speedup 1.0000x reference)
//
#include <hip/hip_runtime.h>

// Bispectrum TM_b = S diag(x) S^T, fp16-split MFMA (AhBh+AhBl+AlBh), round 9:
// ZERO-LDS main kernel. Input (1MB) is L2-resident; LDS staging was the round-8
// bottleneck (fixed ~per-block cost dominated). Now:
//  - pad kernel builds, per batch, 4 dword-shifted fp32 copies (any 8-elem
//    window = two aligned dwordx4) + 4 packed pre-split fp16 copies
//    (u[i] = h16|l16<<16) of the 256-zero-padded signal in d_ws.
//  - main: 1 wave/block, no LDS/barriers; 20 equal-work chunk-blocks per batch
//    (triangle tiles + zero-chunk skip, kbn=2 each); gathers windows straight
//    from L2; B fragments unpack via 2 bitops/word (split precomputed);
//    A products split via v_cvt_pkrtz. Partials to d_ws.
//  - reduce: sums K-split partials, scales, writes tile + LDS-transposed
//    mirror (both writes coalesced).
// MFMA facts (HW-verified m89 + rounds 3/8 passing): A-row/B-col = lane&15;
// k<->slot bijection ours (k = g*8+j both sides); C/D col=lane&15,
// row=(lane>>4)*4+reg.

#define LEN 256
#define NT 8
#define PLANE 4104                    // dwords per shifted copy plane
#define BSTRIDE (8 * PLANE)           // per-batch dwords in P region (4 f32 + 4 packed)
#define QOFF ((size_t)32 * BSTRIDE)   // partials offset in d_ws (dwords)

typedef _Float16 f16x8 __attribute__((ext_vector_type(8)));
typedef float    f32x4 __attribute__((ext_vector_type(4)));

// 20 equal-work blocks per batch: {ti, tj, kb0, _}; kbn = 2 always. ti >= tj.
__constant__ uchar4 kBlockTab[20] = {
    {0,0,0,0},{0,0,2,0},{0,0,4,0},{0,0,6,0},
    {1,0,2,0},{1,0,4,0},{1,0,6,0},
    {1,1,2,0},{1,1,4,0},{1,1,6,0},
    {2,0,4,0},{2,0,6,0},
    {2,1,4,0},{2,1,6,0},
    {2,2,4,0},{2,2,6,0},
    {3,0,6,0},{3,1,6,0},{3,2,6,0},{3,3,6,0}};
// 10 triangle tile-pairs: {ti, tj, slot_base, slot_count}
__constant__ uchar4 kPairTab[10] = {
    {0,0,0,4},{1,0,4,3},{1,1,7,3},{2,0,10,2},{2,1,12,2},{2,2,14,2},
    {3,0,16,1},{3,1,17,1},{3,2,18,1},{3,3,19,1}};

// split pair of f32 -> (hi fp16-pair bits, residual fp16-pair bits)
static __device__ __forceinline__ void split2(float a0, float a1, uint& hb, uint& lb) {
    auto h = __builtin_amdgcn_cvt_pkrtz(a0, a1);
    float e0 = a0 - (float)h[0];
    float e1 = a1 - (float)h[1];
    auto e = __builtin_amdgcn_cvt_pkrtz(e0, e1);
    __builtin_memcpy(&hb, &h, 4);
    __builtin_memcpy(&lb, &e, 4);
}
// split single f32 -> packed u = h16 | l16<<16
static __device__ __forceinline__ uint split1(float v) {
    auto h = __builtin_amdgcn_cvt_pkrtz(v, v);
    float e = v - (float)h[0];
    auto l = __builtin_amdgcn_cvt_pkrtz(e, e);
    uint uh, ul;
    __builtin_memcpy(&uh, &h, 4);
    __builtin_memcpy(&ul, &l, 4);
    return (uh & 0xffffu) | (ul << 16);
}
static __device__ __forceinline__ f16x8 mkf(const uint* u) {
    f16x8 v;
    __builtin_memcpy(&v, u, 16);
    return v;
}

// Build shifted fp32 + packed-split copies of the padded signal.
// Plane c holds X at slot c+i (i.e. plane_c[c+i] = Xpad[i]), so a window
// starting at element p0 is 16B-aligned in plane c = (-p0)&3 at slot p0+c.
__global__ __launch_bounds__(256) void bispec_pad(const float* __restrict__ x,
                                                  float* __restrict__ P) {
    const int b = blockIdx.x, tid = threadIdx.x;
    const float* xb = x + b * (NT * LEN);
    float* Fb = P + (size_t)b * BSTRIDE;
    uint*  Ub = (uint*)(Fb + 4 * PLANE);
    for (int c = 0; c < 4; ++c) {
        for (int i = tid; i < PLANE; i += 256) {
            int j = i - c;                 // padded-signal element index
            float v = 0.0f;
            if (j >= 0 && j < 4096) {
                int jj = j & 511;
                if (jj >= 256) v = xb[(j >> 9) * 256 + (jj - 256)];
            }
            Fb[c * PLANE + i] = v;
            Ub[c * PLANE + i] = split1(v);
        }
    }
}

template <bool PARTIAL>
__global__ __launch_bounds__(64, 2) void bispec_main(const float* __restrict__ P,
                                                     float* __restrict__ dst) {
    const int b = blockIdx.y, bx = blockIdx.x;
    int ti, tj, kb0, kbn;
    if (PARTIAL) {
        uchar4 e = kBlockTab[bx];
        ti = e.x; tj = e.y; kb0 = e.z; kbn = 2;
    } else {
        uchar4 e = kPairTab[bx];
        ti = e.x; tj = e.y; kb0 = 2 * ti; kbn = 8 - 2 * ti;
    }
    const int l1b = ti << 6, l2b = tj << 6;
    const int l = threadIdx.x, cg = l & 15, g = l >> 4;
    const float* F = P + (size_t)b * BSTRIDE;
    const uint*  U = (const uint*)(F + 4 * PLANE);

    f32x4 acc[4][4];
    #pragma unroll
    for (int mi = 0; mi < 4; ++mi)
        #pragma unroll
        for (int ni = 0; ni < 4; ++ni) acc[mi][ni] = 0.0f;

    for (int t = 0; t < NT; ++t) {
        const int tB = t * 512 + 256;          // padded index of n=0
        const int cA = tB + g * 8 - l1b - cg;
        const int cB = tB + g * 8 - l2b - cg;
        const int cX = tB + g * 8;

        for (int kk = 0; kk < kbn; ++kk) {
            const int kb = kb0 + kk;
            // x[n] octet (plane 0: cX + kb*32 is 0 mod 4, broadcast per g-group)
            const float4* xp = (const float4*)(F + cX + kb * 32);
            const float4 x0 = xp[0], x1 = xp[1];
            const float xn[8] = {x0.x, x0.y, x0.z, x0.w, x1.x, x1.y, x1.z, x1.w};

            // A fragments: split(x[n] * x[n-row])
            f16x8 ah[4], al[4];
            #pragma unroll
            for (int mi = 0; mi < 4; ++mi) {
                const int p0 = cA + kb * 32 - mi * 16;
                const int c = (-p0) & 3;
                const float4* wp = (const float4*)(F + c * PLANE + (p0 + c));
                const float4 w0 = wp[0], w1 = wp[1];
                const float wv[8] = {w0.x, w0.y, w0.z, w0.w, w1.x, w1.y, w1.z, w1.w};
                uint Ahp[4], Alp[4];
                #pragma unroll
                for (int p = 0; p < 4; ++p)
                    split2(xn[2 * p] * wv[2 * p], xn[2 * p + 1] * wv[2 * p + 1],
                           Ahp[p], Alp[p]);
                ah[mi] = mkf(Ahp); al[mi] = mkf(Alp);
            }

            // B fragments: pre-split packed gather, 2 bitops per word
            #pragma unroll
            for (int ni = 0; ni < 4; ++ni) {
                const int p0 = cB + kb * 32 - ni * 16;
                const int c = (-p0) & 3;
                const uint4* up = (const uint4*)(U + c * PLANE + (p0 + c));
                const uint4 u0 = up[0], u1 = up[1];
                const uint uu[8] = {u0.x, u0.y, u0.z, u0.w, u1.x, u1.y, u1.z, u1.w};
                uint Bhp[4], Blp[4];
                #pragma unroll
                for (int p = 0; p < 4; ++p) {
                    Bhp[p] = (uu[2 * p] & 0xffffu) | (uu[2 * p + 1] << 16);
                    Blp[p] = (uu[2 * p] >> 16) | (uu[2 * p + 1] & 0xffff0000u);
                }
                const f16x8 bh = mkf(Bhp), bl = mkf(Blp);
                #pragma unroll
                for (int mi = 0; mi < 4; ++mi) {
                    acc[mi][ni] = __builtin_amdgcn_mfma_f32_16x16x32_f16(ah[mi], bh, acc[mi][ni], 0, 0, 0);
                    acc[mi][ni] = __builtin_amdgcn_mfma_f32_16x16x32_f16(ah[mi], bl, acc[mi][ni], 0, 0, 0);
                    acc[mi][ni] = __builtin_amdgcn_mfma_f32_16x16x32_f16(al[mi], bh, acc[mi][ni], 0, 0, 0);
                }
            }
        }
    }

    if (PARTIAL) {
        float* ob = dst + ((size_t)b * 20 + bx) * 4096;
        #pragma unroll
        for (int mi = 0; mi < 4; ++mi)
            #pragma unroll
            for (int ni = 0; ni < 4; ++ni)
                #pragma unroll
                for (int q = 0; q < 4; ++q)
                    ob[(mi * 16 + g * 4 + q) * 64 + ni * 16 + cg] = acc[mi][ni][q];
    } else {
        const float s = 1.0f / (float)(LEN * NT);
        float* ob = dst + (size_t)b * (LEN * LEN);
        #pragma unroll
        for (int mi = 0; mi < 4; ++mi)
            #pragma unroll
            for (int ni = 0; ni < 4; ++ni)
                #pragma unroll
                for (int q = 0; q < 4; ++q) {
                    const float v = acc[mi][ni][q] * s;
                    const int r = l1b + mi * 16 + g * 4 + q;
                    const int cc = l2b + ni * 16 + cg;
                    ob[(size_t)r * LEN + cc] = v;
                    if (ti != tj) ob[(size_t)cc * LEN + r] = v;
                }
    }
}

// Sum K-split partials, scale, write tile + LDS-transposed mirror (coalesced).
__global__ __launch_bounds__(256) void bispec_reduce(const float* __restrict__ ws,
                                                     float* __restrict__ out) {
    __shared__ float tile[64][65];
    const int p = blockIdx.x, b = blockIdx.y;
    uchar4 e = kPairTab[p];
    const int ii = e.x, jj = e.y, s = e.z, c = e.w;
    const float* base = ws + ((size_t)b * 20 + s) * 4096;
    float* ob = out + (size_t)b * (LEN * LEN);
    const float scale = 1.0f / (float)(LEN * NT);
    for (int k = threadIdx.x; k < 4096; k += 256) {
        float v = base[k];
        for (int q = 1; q < c; ++q) v += base[(size_t)q * 4096 + k];
        v *= scale;
        const int r = k >> 6, cc = k & 63;
        tile[r][cc] = v;
        ob[(size_t)(ii * 64 + r) * LEN + jj * 64 + cc] = v;
    }
    if (ii != jj) {
        __syncthreads();
        for (int k = threadIdx.x; k < 4096; k += 256) {
            const int r = k >> 6, cc = k & 63;
            ob[(size_t)(jj * 64 + r) * LEN + ii * 64 + cc] = tile[cc][r];
        }
    }
}

extern "C" void kernel_launch(void* const* d_in, const int* in_sizes, int n_in,
                              void* d_out, int out_size, void* d_ws, size_t ws_size,
                              hipStream_t stream) {
    const float* x = (const float*)d_in[0];   // [32, 8, 256] fp32
    float* out = (float*)d_out;               // [32*256*256] source ++ [32*8*256] target
    float* P = (float*)d_ws;

    const size_t needP = QOFF * sizeof(float);                               // 4.2 MB
    const size_t need  = (QOFF + (size_t)32 * 20 * 4096) * sizeof(float);    // 14.7 MB

    if (ws_size >= need) {
        float* Q = P + QOFF;
        bispec_pad<<<dim3(32), dim3(256), 0, stream>>>(x, P);
        bispec_main<true><<<dim3(20, 32), dim3(64), 0, stream>>>(P, Q);
        bispec_reduce<<<dim3(10, 32), dim3(256), 0, stream>>>(Q, out);
    } else if (ws_size >= needP) {
        // fallback: direct triangle write (imbalanced but correct)
        bispec_pad<<<dim3(32), dim3(256), 0, stream>>>(x, P);
        bispec_main<false><<<dim3(10, 32), dim3(64), 0, stream>>>(P, out);
    }

    // Second tuple element: target passed through unchanged.
    (void)hipMemcpyAsync(out + (size_t)32 * LEN * LEN, x,
                         (size_t)32 * NT * LEN * sizeof(float),
                         hipMemcpyDeviceToDevice, stream);
}

// Round 10
// 87.044 us; speedup vs baseline: 1.5024x; 1.5024x over previous
//
#include <hip/hip_runtime.h>

// Bispectrum TM_b = S diag(x) S^T, fp16-split 3-pass MFMA (AhBh+AhBl+AlBh).
// Round 10: round-8 skeleton (4-wave blocks, LDS staging, 20 balanced
// chunk-blocks, tree-reduce epilogue, separate reduce kernel) with the
// latency fixes the PMC data demanded:
//  - per-lane window parity is CONSTANT (== cg&1): parity base hoisted once,
//    all window reads are ds_read_b64 at compile-time immediate offsets
//    (bases biased by -48 so offsets are non-negative).
//  - full unroll of the 4 (t,kb) units/wave -> 136 independent LDS reads for
//    the compiler to pipeline (ILP to hide ~120cyc ds latency at low TLP).
//  - parity copy at 4105 (==9 mod 32): kills round-3's 4.19M bank conflicts
//    (4097 == 1 mod 32 aliased odd lanes onto even-lane banks).
// MFMA facts (HW-verified m89 + rounds 3/8/9 passing): A-row/B-col = lane&15;
// k<->slot bijection ours (k = g*8+j both sides); C/D col=lane&15,
// row=(lane>>4)*4+reg.

#define LEN 256
#define NT 8
#define F1OFF 4105      // parity copy base (odd; ==9 mod 32)
#define REDSTR 68       // reduction buffer stride (16B-aligned, 2-way banks max)
#define SMEM_DW 8704    // max(staging 4105+4096=8201, reduction 2*64*68=8704)

typedef _Float16 f16x8 __attribute__((ext_vector_type(8)));
typedef float    f32x4 __attribute__((ext_vector_type(4)));

// 20 equal-work blocks per batch: {ti, tj, kb0, _}; 2 kb-chunks each. ti>=tj.
__constant__ uchar4 kBlockTab[20] = {
    {0,0,0,0},{0,0,2,0},{0,0,4,0},{0,0,6,0},
    {1,0,2,0},{1,0,4,0},{1,0,6,0},
    {1,1,2,0},{1,1,4,0},{1,1,6,0},
    {2,0,4,0},{2,0,6,0},
    {2,1,4,0},{2,1,6,0},
    {2,2,4,0},{2,2,6,0},
    {3,0,6,0},{3,1,6,0},{3,2,6,0},{3,3,6,0}};
// 10 triangle tile-pairs: {ti, tj, slot_base, slot_count}
__constant__ uchar4 kPairTab[10] = {
    {0,0,0,4},{1,0,4,3},{1,1,7,3},{2,0,10,2},{2,1,12,2},{2,2,14,2},
    {3,0,16,1},{3,1,17,1},{3,2,18,1},{3,3,19,1}};

// split pair of f32 -> (hi fp16-pair bits, residual fp16-pair bits)
static __device__ __forceinline__ void split2(float a0, float a1, uint& hb, uint& lb) {
    auto h = __builtin_amdgcn_cvt_pkrtz(a0, a1);
    float e0 = a0 - (float)h[0];
    float e1 = a1 - (float)h[1];
    auto e = __builtin_amdgcn_cvt_pkrtz(e0, e1);
    __builtin_memcpy(&hb, &h, 4);
    __builtin_memcpy(&lb, &e, 4);
}
static __device__ __forceinline__ f16x8 mkf(const uint* u) {
    f16x8 v;
    __builtin_memcpy(&v, u, 16);
    return v;
}

template <bool PARTIAL>
__global__ __launch_bounds__(256, 3) void bispec_main(const float* __restrict__ x,
                                                      float* __restrict__ dst) {
    __shared__ float fs[SMEM_DW];
    const int b = blockIdx.y, bx = blockIdx.x;

    int ti, tj, kb0, nkp;
    if (PARTIAL) {
        uchar4 e = kBlockTab[bx];
        ti = e.x; tj = e.y; kb0 = e.z; nkp = 1;
    } else {
        uchar4 e = kPairTab[bx];
        ti = e.x; tj = e.y; kb0 = 2 * ti; nkp = 4 - ti;   // ti >= tj in table
    }
    const int l1b = ti << 6, l2b = tj << 6;
    const int tid = threadIdx.x;
    const int w = tid >> 6, l = tid & 63, cg = l & 15, g = l >> 4;

    // ---- stage padded signal: F0 @0, parity copy F1 @4105 ----
    const float* xb = x + b * (NT * LEN);
    for (int i = tid; i < 4096; i += 256) {
        int j = i & 511;
        float v = (j >= 256) ? xb[(i >> 9) * 256 + (j - 256)] : 0.0f;
        fs[i] = v;
        fs[F1OFF + i] = v;
    }
    __syncthreads();

    // Per-lane parity base: window starts are == cg (mod 2) ALWAYS.
    const float* fW = fs + ((cg & 1) ? F1OFF : 0);

    f32x4 acc[4][4];
    #pragma unroll
    for (int mi = 0; mi < 4; ++mi)
        #pragma unroll
        for (int ni = 0; ni < 4; ++ni) acc[mi][ni] = 0.0f;

    #pragma unroll
    for (int tt = 0; tt < 2; ++tt) {
        const int t  = w + tt * 4;             // wave w covers t = {w, w+4}
        const int xB0 = t * 512 + 256 + g * 8 + kb0 * 32;

        for (int kp = 0; kp < nkp; ++kp) {     // 1 iter when PARTIAL
            const int xB = xB0 + kp * 64;
            const float* pX = fs + xB;               // 16B-aligned
            const float* pA = fW + (xB - l1b - cg - 48);  // even dword addr
            const float* pB = fW + (xB - l2b - cg - 48);

            #pragma unroll
            for (int kk = 0; kk < 2; ++kk) {   // two K=32 units, static offsets
                const int ko = kk * 32;
                const float4 x0 = *(const float4*)(pX + ko);
                const float4 x1 = *(const float4*)(pX + ko + 4);
                const float xn[8] = {x0.x, x0.y, x0.z, x0.w, x1.x, x1.y, x1.z, x1.w};

                // A fragments: split(x[n] * x[n-row]); window offset static
                f16x8 ah[4], al[4];
                #pragma unroll
                for (int mi = 0; mi < 4; ++mi) {
                    const int off = ko + 48 - mi * 16;   // >= 0, compile-time
                    float wv[8];
                    #pragma unroll
                    for (int p = 0; p < 4; ++p) {
                        const float2 d = *(const float2*)(pA + off + 2 * p);
                        wv[2 * p] = d.x; wv[2 * p + 1] = d.y;
                    }
                    uint Ahp[4], Alp[4];
                    #pragma unroll
                    for (int p = 0; p < 4; ++p)
                        split2(xn[2 * p] * wv[2 * p], xn[2 * p + 1] * wv[2 * p + 1],
                               Ahp[p], Alp[p]);
                    ah[mi] = mkf(Ahp); al[mi] = mkf(Alp);
                }

                // B fragments: split(x[n-col]); consumed per ni
                #pragma unroll
                for (int ni = 0; ni < 4; ++ni) {
                    const int off = ko + 48 - ni * 16;
                    float wv[8];
                    #pragma unroll
                    for (int p = 0; p < 4; ++p) {
                        const float2 d = *(const float2*)(pB + off + 2 * p);
                        wv[2 * p] = d.x; wv[2 * p + 1] = d.y;
                    }
                    uint Bhp[4], Blp[4];
                    #pragma unroll
                    for (int p = 0; p < 4; ++p)
                        split2(wv[2 * p], wv[2 * p + 1], Bhp[p], Blp[p]);
                    const f16x8 bh = mkf(Bhp), bl = mkf(Blp);
                    #pragma unroll
                    for (int mi = 0; mi < 4; ++mi) {
                        acc[mi][ni] = __builtin_amdgcn_mfma_f32_16x16x32_f16(ah[mi], bh, acc[mi][ni], 0, 0, 0);
                        acc[mi][ni] = __builtin_amdgcn_mfma_f32_16x16x32_f16(ah[mi], bl, acc[mi][ni], 0, 0, 0);
                        acc[mi][ni] = __builtin_amdgcn_mfma_f32_16x16x32_f16(al[mi], bh, acc[mi][ni], 0, 0, 0);
                    }
                }
            }
        }
    }

    // ---- cross-wave tree reduction (transposed layout, b128 LDS ops) ----
    __syncthreads();
    float* buf0 = fs;
    float* buf1 = fs + 4352;   // 64*68 = 4352
    if (w >= 2) {
        float* bb = (w == 2) ? buf0 : buf1;
        #pragma unroll
        for (int mi = 0; mi < 4; ++mi)
            #pragma unroll
            for (int ni = 0; ni < 4; ++ni)
                *(f32x4*)&bb[(ni * 16 + cg) * REDSTR + mi * 16 + g * 4] = acc[mi][ni];
    }
    __syncthreads();
    if (w < 2) {
        float* bb = (w == 0) ? buf0 : buf1;
        #pragma unroll
        for (int mi = 0; mi < 4; ++mi)
            #pragma unroll
            for (int ni = 0; ni < 4; ++ni)
                acc[mi][ni] += *(f32x4*)&bb[(ni * 16 + cg) * REDSTR + mi * 16 + g * 4];
    }
    __syncthreads();
    if (w == 1) {
        #pragma unroll
        for (int mi = 0; mi < 4; ++mi)
            #pragma unroll
            for (int ni = 0; ni < 4; ++ni)
                *(f32x4*)&buf0[(ni * 16 + cg) * REDSTR + mi * 16 + g * 4] = acc[mi][ni];
    }
    __syncthreads();
    if (w == 0) {
        #pragma unroll
        for (int mi = 0; mi < 4; ++mi)
            #pragma unroll
            for (int ni = 0; ni < 4; ++ni)
                acc[mi][ni] += *(f32x4*)&buf0[(ni * 16 + cg) * REDSTR + mi * 16 + g * 4];

        if (PARTIAL) {
            float* ob = dst + ((size_t)b * 20 + bx) * 4096;
            #pragma unroll
            for (int mi = 0; mi < 4; ++mi)
                #pragma unroll
                for (int ni = 0; ni < 4; ++ni)
                    #pragma unroll
                    for (int q = 0; q < 4; ++q)
                        ob[(mi * 16 + g * 4 + q) * 64 + ni * 16 + cg] = acc[mi][ni][q];
        } else {
            const float s = 1.0f / (float)(LEN * NT);
            float* ob = dst + (size_t)b * (LEN * LEN);
            #pragma unroll
            for (int mi = 0; mi < 4; ++mi)
                #pragma unroll
                for (int ni = 0; ni < 4; ++ni)
                    #pragma unroll
                    for (int q = 0; q < 4; ++q) {
                        const float v = acc[mi][ni][q] * s;
                        const int r = l1b + mi * 16 + g * 4 + q;
                        const int cc = l2b + ni * 16 + cg;
                        ob[(size_t)r * LEN + cc] = v;
                        if (ti != tj) ob[(size_t)cc * LEN + r] = v;
                    }
        }
    }
}

// Sum K-split partials, scale, write tile + LDS-transposed mirror (coalesced).
__global__ __launch_bounds__(256) void bispec_reduce(const float* __restrict__ ws,
                                                     float* __restrict__ out) {
    __shared__ float tile[64][65];
    const int p = blockIdx.x, b = blockIdx.y;
    uchar4 e = kPairTab[p];
    const int ii = e.x, jj = e.y, s = e.z, c = e.w;
    const float* base = ws + ((size_t)b * 20 + s) * 4096;
    float* ob = out + (size_t)b * (LEN * LEN);
    const float scale = 1.0f / (float)(LEN * NT);
    for (int k = threadIdx.x; k < 4096; k += 256) {
        float v = base[k];
        for (int q = 1; q < c; ++q) v += base[(size_t)q * 4096 + k];
        v *= scale;
        const int r = k >> 6, cc = k & 63;
        tile[r][cc] = v;
        ob[(size_t)(ii * 64 + r) * LEN + jj * 64 + cc] = v;
    }
    if (ii != jj) {
        __syncthreads();
        for (int k = threadIdx.x; k < 4096; k += 256) {
            const int r = k >> 6, cc = k & 63;
            ob[(size_t)(jj * 64 + r) * LEN + ii * 64 + cc] = tile[cc][r];
        }
    }
}

extern "C" void kernel_launch(void* const* d_in, const int* in_sizes, int n_in,
                              void* d_out, int out_size, void* d_ws, size_t ws_size,
                              hipStream_t stream) {
    const float* x = (const float*)d_in[0];   // [32, 8, 256] fp32
    float* out = (float*)d_out;               // [32*256*256] source ++ [32*8*256] target

    const size_t ws_need = (size_t)32 * 20 * 4096 * sizeof(float);  // 10.5 MB
    if (ws_size >= ws_need) {
        float* ws = (float*)d_ws;
        bispec_main<true><<<dim3(20, 32), dim3(256), 0, stream>>>(x, ws);
        bispec_reduce<<<dim3(10, 32), dim3(256), 0, stream>>>(ws, out);
    } else {
        // fallback: triangle grid, in-kernel scale + mirror (imbalanced, correct)
        bispec_main<false><<<dim3(10, 32), dim3(256), 0, stream>>>(x, out);
    }

    // Second tuple element: target passed through unchanged.
    (void)hipMemcpyAsync(out + (size_t)32 * LEN * LEN, x,
                         (size_t)32 * NT * LEN * sizeof(float),
                         hipMemcpyDeviceToDevice, stream);
}